// Round 5
// baseline (378.995 us; speedup 1.0000x reference)
//
#include <hip/hip_runtime.h>
#include <math.h>

#define Bv 64
#define Jv 20000
#define TJ 32
#define TB 16
#define NJT 625   // 20000/32
#define NBT 4     // 64/16

// Block = 32 j x 16 b; thread = 1 j x 2 b (register-blocked on b so every
// wave-uniform LDS read of a weight row feeds 2x FMAs). Per-j state (pre1,
// gate bias, LN1 closed-form stats) computed once into LDS, reused by all b.
__global__ __launch_bounds__(256) void pe_fused(
    const float* __restrict__ x, const int* __restrict__ mask,
    const int* __restrict__ atse_idx, const float* __restrict__ fe,
    const float* __restrict__ ae,
    const float* __restrict__ hW1, const float* __restrict__ hb1,
    const float* __restrict__ hl1g, const float* __restrict__ hl1b,
    const float* __restrict__ hW2, const float* __restrict__ hb2,
    const float* __restrict__ hl2g, const float* __restrict__ hl2b,
    const float* __restrict__ gW1, const float* __restrict__ gb1,
    const float* __restrict__ gW2, const float* __restrict__ gb2,
    float* __restrict__ acc_g, float* __restrict__ se_g) {
  __shared__ __align__(16) float s_pre1[TJ * 68];   // [32 j][64k] stride 68
  __shared__ __align__(16) float s_ex[TJ * 4];      // sp, qp, dwp per j
  __shared__ __align__(16) float s_gb[TJ * 28];     // [32 j][24c] stride 28
  __shared__ __align__(16) float s_W2[64 * 32];
  __shared__ __align__(16) float s_gW1h[32 * 24];
  __shared__ __align__(16) float s_gW2[96];
  __shared__ __align__(16) float s_w0[64], s_l1g[64], s_l1b[64], s_hb1[64];
  __shared__ __align__(16) float s_b2[32], s_l2g[32], s_l2b[32];
  __shared__ __align__(16) float s_gb1[24];
  __shared__ float s_gb2[4], s_scal[2];
  // overlay: pre-phase {fe[32*33]=1056, hW1f[2048], ae[32*20]=640, gW1b[384]} = 4128
  //          reduce    {s_e[256*5]=1280, s_h[256*20]=5120} = 6400
  __shared__ __align__(16) float s_ovl[6400];

  int tid = threadIdx.x;
  int btile = blockIdx.x;   // 0..3
  int jtile = blockIdx.y;   // 0..624

  float* s_fe   = s_ovl;            // [32][33]
  float* s_hW1f = s_ovl + 1056;     // [32][64] rows 1..32 of hW1
  float* s_ae   = s_ovl + 3104;     // [32][20]
  float* s_gW1b = s_ovl + 3744;     // [16][24]
  float* s_e    = s_ovl;            // [256][5]
  float* s_h    = s_ovl + 1280;     // [256][20] (16-float chunk + pad, b128-aligned)

  // ---------------- stage ----------------
  for (int i = tid; i < 2048; i += 256) s_W2[i] = hW2[i];
  for (int i = tid; i < 768; i += 256) s_gW1h[i] = gW1[i];
  for (int i = tid; i < 1024; i += 256)
    s_fe[(i >> 5) * 33 + (i & 31)] = fe[(size_t)jtile * 1024 + i];
  for (int i = tid; i < 2048; i += 256) s_hW1f[i] = hW1[64 + i];
  for (int i = tid; i < 384; i += 256) s_gW1b[i] = gW1[768 + i];
  if (tid < 96) s_gW2[tid] = gW2[tid];
  if (tid < 64) {
    s_w0[tid] = hW1[tid]; s_l1g[tid] = hl1g[tid];
    s_l1b[tid] = hl1b[tid]; s_hb1[tid] = hb1[tid];
  }
  if (tid < 32) { s_b2[tid] = hb2[tid]; s_l2g[tid] = hl2g[tid]; s_l2b[tid] = hl2b[tid]; }
  if (tid < 24) s_gb1[tid] = gb1[tid];
  if (tid < 4) s_gb2[tid] = gb2[tid];
  if (tid < 32) {
    int ai = atse_idx[jtile * 32 + tid];
    const float4* av = (const float4*)(ae + (size_t)ai * 16);
#pragma unroll
    for (int q = 0; q < 4; ++q) *(float4*)(s_ae + tid * 20 + q * 4) = av[q];
  }
  __syncthreads();

  // ---------------- per-j pre-compute (8 threads per j) ----------------
  {
    int jp = tid >> 3, ks = tid & 7;
    float a8[8];
#pragma unroll
    for (int kk = 0; kk < 8; ++kk) a8[kk] = s_hb1[ks * 8 + kk];
#pragma unroll 4
    for (int d = 0; d < 32; ++d) {
      float Fd = s_fe[jp * 33 + d];
      const float* wr = s_hW1f + d * 64 + ks * 8;
#pragma unroll
      for (int kk = 0; kk < 8; ++kk) a8[kk] = fmaf(Fd, wr[kk], a8[kk]);
    }
#pragma unroll
    for (int kk = 0; kk < 8; ++kk) s_pre1[jp * 68 + ks * 8 + kk] = a8[kk];

    int c0 = ks * 3;
    float g3[3] = {s_gb1[c0], s_gb1[c0 + 1], s_gb1[c0 + 2]};
#pragma unroll 4
    for (int a = 0; a < 16; ++a) {
      float Av = s_ae[jp * 20 + a];
      const float* gr = s_gW1b + a * 24 + c0;
      g3[0] = fmaf(Av, gr[0], g3[0]);
      g3[1] = fmaf(Av, gr[1], g3[1]);
      g3[2] = fmaf(Av, gr[2], g3[2]);
    }
    s_gb[jp * 28 + c0] = g3[0];
    s_gb[jp * 28 + c0 + 1] = g3[1];
    s_gb[jp * 28 + c0 + 2] = g3[2];
  }
  __syncthreads();

  // ---------------- LN1 closed-form stats per j ----------------
  if (tid < 32) {
    float sp = 0.f, qp = 0.f, dwp = 0.f;
#pragma unroll 8
    for (int k = 0; k < 64; ++k) {
      float p = s_pre1[tid * 68 + k];
      float w = s_w0[k];
      sp += p;
      qp = fmaf(p, p, qp);
      dwp = fmaf(p, w, dwp);
    }
    ((float4*)s_ex)[tid] = make_float4(sp, qp, dwp, 0.f);
  } else if (tid == 32) {
    float sw = 0.f, qw = 0.f;
    for (int k = 0; k < 64; ++k) {
      float w = s_w0[k];
      sw += w;
      qw = fmaf(w, w, qw);
    }
    s_scal[0] = sw;
    s_scal[1] = qw;
  }
  __syncthreads();

  // ---------------- compute: thread = (j = tid&31) x 2 b's ----------------
  int jl = tid & 31, bg = tid >> 5;
  int b0 = btile * TB + bg * 2;
  size_t xoff = (size_t)jtile * 32 + jl;
  float xv0 = x[(size_t)b0 * Jv + xoff];
  float xv1 = x[(size_t)(b0 + 1) * Jv + xoff];
  int m0 = mask[(size_t)b0 * Jv + xoff];
  int m1 = mask[(size_t)(b0 + 1) * Jv + xoff];

  float4 ex = ((const float4*)s_ex)[jl];
  float Sw0 = s_scal[0], Qw0 = s_scal[1];
  float mu10 = fmaf(xv0, Sw0, ex.x) * 0.015625f;
  float Et20 = fmaf(xv0 * xv0, Qw0, fmaf(2.0f * xv0, ex.z, ex.y)) * 0.015625f;
  float rs10 = rsqrtf(fmaxf(Et20 - mu10 * mu10, 0.f) + 1e-5f);
  float nm10 = -mu10 * rs10;
  float mu11 = fmaf(xv1, Sw0, ex.x) * 0.015625f;
  float Et21 = fmaf(xv1 * xv1, Qw0, fmaf(2.0f * xv1, ex.z, ex.y)) * 0.015625f;
  float rs11 = rsqrtf(fmaxf(Et21 - mu11 * mu11, 0.f) + 1e-5f);
  float nm11 = -mu11 * rs11;

  float h2[2][32];
#pragma unroll
  for (int q = 0; q < 8; ++q) {
    float4 bb4 = ((const float4*)s_b2)[q];
    h2[0][4 * q] = bb4.x; h2[0][4 * q + 1] = bb4.y;
    h2[0][4 * q + 2] = bb4.z; h2[0][4 * q + 3] = bb4.w;
    h2[1][4 * q] = bb4.x; h2[1][4 * q + 1] = bb4.y;
    h2[1][4 * q + 2] = bb4.z; h2[1][4 * q + 3] = bb4.w;
  }
  const float4* pr4 = (const float4*)(s_pre1 + jl * 68);
#pragma unroll 4
  for (int k4 = 0; k4 < 16; ++k4) {
    float4 p = pr4[k4];
    float4 w04 = ((const float4*)s_w0)[k4];
    float4 g4 = ((const float4*)s_l1g)[k4];
    float4 b4 = ((const float4*)s_l1b)[k4];
    float a0[4], a1[4];
    a0[0] = fmaxf(fmaf(fmaf(fmaf(xv0, w04.x, p.x), rs10, nm10), g4.x, b4.x), 0.f);
    a0[1] = fmaxf(fmaf(fmaf(fmaf(xv0, w04.y, p.y), rs10, nm10), g4.y, b4.y), 0.f);
    a0[2] = fmaxf(fmaf(fmaf(fmaf(xv0, w04.z, p.z), rs10, nm10), g4.z, b4.z), 0.f);
    a0[3] = fmaxf(fmaf(fmaf(fmaf(xv0, w04.w, p.w), rs10, nm10), g4.w, b4.w), 0.f);
    a1[0] = fmaxf(fmaf(fmaf(fmaf(xv1, w04.x, p.x), rs11, nm11), g4.x, b4.x), 0.f);
    a1[1] = fmaxf(fmaf(fmaf(fmaf(xv1, w04.y, p.y), rs11, nm11), g4.y, b4.y), 0.f);
    a1[2] = fmaxf(fmaf(fmaf(fmaf(xv1, w04.z, p.z), rs11, nm11), g4.z, b4.z), 0.f);
    a1[3] = fmaxf(fmaf(fmaf(fmaf(xv1, w04.w, p.w), rs11, nm11), g4.w, b4.w), 0.f);
#pragma unroll
    for (int u = 0; u < 4; ++u) {
      float va0 = a0[u], va1 = a1[u];
      const float4* row = (const float4*)(s_W2 + (k4 * 4 + u) * 32);
#pragma unroll
      for (int q = 0; q < 8; ++q) {
        float4 w = row[q];
        h2[0][4 * q]     = fmaf(va0, w.x, h2[0][4 * q]);
        h2[0][4 * q + 1] = fmaf(va0, w.y, h2[0][4 * q + 1]);
        h2[0][4 * q + 2] = fmaf(va0, w.z, h2[0][4 * q + 2]);
        h2[0][4 * q + 3] = fmaf(va0, w.w, h2[0][4 * q + 3]);
        h2[1][4 * q]     = fmaf(va1, w.x, h2[1][4 * q]);
        h2[1][4 * q + 1] = fmaf(va1, w.y, h2[1][4 * q + 1]);
        h2[1][4 * q + 2] = fmaf(va1, w.z, h2[1][4 * q + 2]);
        h2[1][4 * q + 3] = fmaf(va1, w.w, h2[1][4 * q + 3]);
      }
    }
  }

  // ---------------- LN2 + relu + gate, per bb ----------------
  float e[2][4];
#pragma unroll
  for (int bb = 0; bb < 2; ++bb) {
    float s = 0.f;
#pragma unroll
    for (int d = 0; d < 32; ++d) s += h2[bb][d];
    float mu2 = s * 0.03125f;
    float vv = 0.f;
#pragma unroll
    for (int d = 0; d < 32; ++d) { float dd = h2[bb][d] - mu2; vv = fmaf(dd, dd, vv); }
    float rs2 = rsqrtf(vv * 0.03125f + 1e-5f);
#pragma unroll
    for (int d = 0; d < 32; ++d)
      h2[bb][d] = fmaxf(fmaf((h2[bb][d] - mu2) * rs2, s_l2g[d], s_l2b[d]), 0.f);

    float g1[24];
    const float4* gbv = (const float4*)(s_gb + jl * 28);
#pragma unroll
    for (int c4 = 0; c4 < 6; ++c4) {
      float4 v = gbv[c4];
      g1[4 * c4] = v.x; g1[4 * c4 + 1] = v.y;
      g1[4 * c4 + 2] = v.z; g1[4 * c4 + 3] = v.w;
    }
#pragma unroll 8
    for (int i = 0; i < 32; ++i) {
      float hv = h2[bb][i];
      const float4* row = (const float4*)(s_gW1h + i * 24);
#pragma unroll
      for (int c4 = 0; c4 < 6; ++c4) {
        float4 w = row[c4];
        g1[4 * c4]     = fmaf(hv, w.x, g1[4 * c4]);
        g1[4 * c4 + 1] = fmaf(hv, w.y, g1[4 * c4 + 1]);
        g1[4 * c4 + 2] = fmaf(hv, w.z, g1[4 * c4 + 2]);
        g1[4 * c4 + 3] = fmaf(hv, w.w, g1[4 * c4 + 3]);
      }
    }
    float r0 = s_gb2[0], r1 = s_gb2[1], r2 = s_gb2[2], r3 = s_gb2[3];
#pragma unroll
    for (int c = 0; c < 24; ++c) {
      float gv = fmaxf(g1[c], 0.0f);
      float4 w = ((const float4*)s_gW2)[c];
      r0 = fmaf(gv, w.x, r0);
      r1 = fmaf(gv, w.y, r1);
      r2 = fmaf(gv, w.z, r2);
      r3 = fmaf(gv, w.w, r3);
    }
    r0 = fminf(fmaxf(r0, -10.f), 10.f);
    r1 = fminf(fmaxf(r1, -10.f), 10.f);
    r2 = fminf(fmaxf(r2, -10.f), 10.f);
    r3 = fminf(fmaxf(r3, -10.f), 10.f);
    bool act = (bb ? m1 : m0) != 0;
    e[bb][0] = act ? __expf(r0 - 10.f) : 0.f;
    e[bb][1] = act ? __expf(r1 - 10.f) : 0.f;
    e[bb][2] = act ? __expf(r2 - 10.f) : 0.f;
    e[bb][3] = act ? __expf(r3 - 10.f) : 0.f;
  }

  // ---------------- reduce: 2 bb x 2 d-chunks, direct atomics ----------------
  int rbg = tid >> 5, rw = (tid >> 3) & 3, rd = tid & 7;
#pragma unroll
  for (int bb = 0; bb < 2; ++bb) {
#pragma unroll
    for (int ch = 0; ch < 2; ++ch) {
      __syncthreads();   // protect previous sub-round's reads
      if (ch == 0) {
        s_e[tid * 5 + 0] = e[bb][0];
        s_e[tid * 5 + 1] = e[bb][1];
        s_e[tid * 5 + 2] = e[bb][2];
        s_e[tid * 5 + 3] = e[bb][3];
      }
#pragma unroll
      for (int q = 0; q < 4; ++q)
        *(float4*)(s_h + tid * 20 + q * 4) =
            make_float4(h2[bb][ch * 16 + 4 * q], h2[bb][ch * 16 + 4 * q + 1],
                        h2[bb][ch * 16 + 4 * q + 2], h2[bb][ch * 16 + 4 * q + 3]);
      __syncthreads();
      float acc0 = 0.f, acc1 = 0.f, sesum = 0.f;
#pragma unroll 8
      for (int jj = 0; jj < 32; ++jj) {
        int slot = rbg * 32 + jj;
        float ev = s_e[slot * 5 + rw];
        float2 hv = *(const float2*)(s_h + slot * 20 + rd * 2);
        acc0 = fmaf(ev, hv.x, acc0);
        acc1 = fmaf(ev, hv.y, acc1);
        sesum += ev;
      }
      int bidx = btile * TB + rbg * 2 + bb;
      atomicAdd(&acc_g[(size_t)bidx * 128 + rw * 32 + ch * 16 + rd * 2], acc0);
      atomicAdd(&acc_g[(size_t)bidx * 128 + rw * 32 + ch * 16 + rd * 2 + 1], acc1);
      if (ch == 0 && rd == 0) atomicAdd(&se_g[bidx * 4 + rw], sesum);
    }
  }
}

// ---------------- per-b tail: normalize, c-layer, encoder MLP ----------------
__global__ __launch_bounds__(64) void pe_tail(
    const float* __restrict__ acc_g, const float* __restrict__ se_g,
    const float* __restrict__ cW, const float* __restrict__ cb,
    const float* __restrict__ clng, const float* __restrict__ clnb,
    const float* __restrict__ eW1, const float* __restrict__ eb1,
    const float* __restrict__ eW2, const float* __restrict__ eb2,
    float* __restrict__ out) {
  int b = blockIdx.x;
  int lane = threadIdx.x;  // 64 threads = 1 wave
  __shared__ float s_hs[128], s_comb[32], s_e1[128];

  float se0 = se_g[b * 4 + 0];
  bool empty = !(se0 > 0.0f);
  float inv[4];
#pragma unroll
  for (int w = 0; w < 4; ++w) {
    float sw = se_g[b * 4 + w];
    inv[w] = empty ? 0.0f : 1.0f / sw;
  }
  s_hs[lane] = acc_g[b * 128 + lane] * inv[lane >> 5];
  s_hs[lane + 64] = acc_g[b * 128 + lane + 64] * inv[(lane + 64) >> 5];
  __syncthreads();

  if (lane < 32) {
    float cp = cb[lane];
#pragma unroll 8
    for (int i = 0; i < 128; ++i) cp = fmaf(s_hs[i], cW[i * 32 + lane], cp);
    float ssum = cp;
#pragma unroll
    for (int off = 16; off > 0; off >>= 1) ssum += __shfl_xor(ssum, off, 32);
    float mu = ssum * (1.0f / 32.0f);
    float dd = cp - mu;
    float sq = dd * dd;
#pragma unroll
    for (int off = 16; off > 0; off >>= 1) sq += __shfl_xor(sq, off, 32);
    float rs = rsqrtf(sq * (1.0f / 32.0f) + 1e-5f);
    float comb = fmaxf(fmaf(dd * rs, clng[lane], clnb[lane]), 0.0f);
    if (empty) comb = 0.0f;
    s_comb[lane] = comb;
  }
  __syncthreads();

  float v0 = eb1[lane], v1 = eb1[lane + 64];
#pragma unroll
  for (int i = 0; i < 32; ++i) {
    float c = s_comb[i];
    v0 = fmaf(c, eW1[i * 128 + lane], v0);
    v1 = fmaf(c, eW1[i * 128 + lane + 64], v1);
  }
  float ssum = v0 + v1;
#pragma unroll
  for (int off = 32; off > 0; off >>= 1) ssum += __shfl_xor(ssum, off, 64);
  float mu = ssum * (1.0f / 128.0f);
  float d0 = v0 - mu, d1 = v1 - mu;
  float sq = fmaf(d0, d0, d1 * d1);
#pragma unroll
  for (int off = 32; off > 0; off >>= 1) sq += __shfl_xor(sq, off, 64);
  float rs = rsqrtf(sq * (1.0f / 128.0f) + 1e-5f);
  s_e1[lane] = fmaxf(d0 * rs, 0.0f);
  s_e1[lane + 64] = fmaxf(d1 * rs, 0.0f);
  __syncthreads();

  float v = eb2[lane];
#pragma unroll 8
  for (int i = 0; i < 128; ++i) v = fmaf(s_e1[i], eW2[i * 64 + lane], v);
  ssum = v;
#pragma unroll
  for (int off = 32; off > 0; off >>= 1) ssum += __shfl_xor(ssum, off, 64);
  mu = ssum * (1.0f / 64.0f);
  float dv = v - mu;
  sq = dv * dv;
#pragma unroll
  for (int off = 32; off > 0; off >>= 1) sq += __shfl_xor(sq, off, 64);
  rs = rsqrtf(sq * (1.0f / 64.0f) + 1e-5f);
  float o = fmaxf(dv * rs, 0.0f);
  if (lane < 32)
    out[b * 32 + lane] = o;                       // mu
  else
    out[Bv * 32 + b * 32 + (lane - 32)] = o;      // logvar
}

extern "C" void kernel_launch(void* const* d_in, const int* in_sizes, int n_in,
                              void* d_out, int out_size, void* d_ws, size_t ws_size,
                              hipStream_t stream) {
  const float* x    = (const float*)d_in[0];
  const int* mask   = (const int*)d_in[1];
  const int* atse   = (const int*)d_in[2];
  const float* fe   = (const float*)d_in[3];
  const float* ae   = (const float*)d_in[4];
  const float* hW1  = (const float*)d_in[5];
  const float* hb1  = (const float*)d_in[6];
  const float* hl1g = (const float*)d_in[7];
  const float* hl1b = (const float*)d_in[8];
  const float* hW2  = (const float*)d_in[9];
  const float* hb2  = (const float*)d_in[10];
  const float* hl2g = (const float*)d_in[11];
  const float* hl2b = (const float*)d_in[12];
  const float* gW1  = (const float*)d_in[13];
  const float* gb1  = (const float*)d_in[14];
  const float* gW2  = (const float*)d_in[15];
  const float* gb2  = (const float*)d_in[16];
  const float* cW   = (const float*)d_in[17];
  const float* cb   = (const float*)d_in[18];
  const float* clng = (const float*)d_in[19];
  const float* clnb = (const float*)d_in[20];
  const float* eW1  = (const float*)d_in[21];
  const float* eb1  = (const float*)d_in[22];
  const float* eW2  = (const float*)d_in[23];
  const float* eb2  = (const float*)d_in[24];
  float* out = (float*)d_out;

  float* ws = (float*)d_ws;
  float* accg = ws;                 // B*128 floats
  float* seg  = accg + Bv * 128;    // B*4 floats

  hipMemsetAsync(accg, 0, (Bv * 128 + Bv * 4) * sizeof(float), stream);

  pe_fused<<<dim3(NBT, NJT), dim3(256), 0, stream>>>(
      x, mask, atse, fe, ae, hW1, hb1, hl1g, hl1b, hW2, hb2, hl2g, hl2b,
      gW1, gb1, gW2, gb2, accg, seg);
  pe_tail<<<dim3(Bv), dim3(64), 0, stream>>>(
      accg, seg, cW, cb, clng, clnb, eW1, eb1, eW2, eb2, out);
}